// Round 4
// baseline (167.664 us; speedup 1.0000x reference)
//
#include <hip/hip_runtime.h>
#include <hip/hip_bf16.h>

typedef __attribute__((ext_vector_type(8)))  short short8;
typedef __attribute__((ext_vector_type(4)))  short short4v;
typedef __attribute__((ext_vector_type(4)))  float f32x4;
typedef __attribute__((ext_vector_type(16))) float f32x16;

static __device__ inline short f2bf(float f) {
    union { __hip_bfloat16 h; unsigned short u; } cv;
    cv.h = __float2bfloat16(f);
    return (short)cv.u;
}

// ---------------------------------------------------------------------------
// Kernel 0: zero the halo of a padded [8][66][66][C] bf16 image buffer.
// job = (b, halo-pixel p of 260, channel-chunk of 8 shorts).
// ---------------------------------------------------------------------------
__global__ __launch_bounds__(256) void k_zero_halo(short* __restrict__ p, int ch8) {
    int id = blockIdx.x * 256 + threadIdx.x;
    int njobs = 8 * 260 * ch8;
    if (id >= njobs) return;
    int c8 = id % ch8;
    int rest = id / ch8;
    int px = rest % 260;
    int b = rest / 260;
    int row, col;
    if (px < 66)       { row = 0;  col = px; }
    else if (px < 132) { row = 65; col = px - 66; }
    else { int q = px - 132; row = 1 + (q >> 1); col = (q & 1) ? 65 : 0; }
    short8 z = {0, 0, 0, 0, 0, 0, 0, 0};
    *(short8*)(p + ((size_t)((b * 66 + row) * 66 + col)) * (ch8 * 8) + c8 * 8) = z;
}

// ---------------------------------------------------------------------------
// Kernel 1: content [B,512,64,64] f32 -> xTp [B,66,66,512] bf16 (interior)
// ---------------------------------------------------------------------------
__global__ __launch_bounds__(256) void k_transpose(const float* __restrict__ x,
                                                   short* __restrict__ xTp) {
    __shared__ float lds[128][65];
    int blk = blockIdx.x;
    int b = blk >> 6, h = blk & 63;
    int t = threadIdx.x;
    for (int cb = 0; cb < 4; ++cb) {
        #pragma unroll
        for (int k = 0; k < 32; ++k) {
            int idx = k * 256 + t;
            int c = idx >> 6, w = idx & 63;
            lds[c][w] = x[(((size_t)b * 512 + cb * 128 + c) * 64 + h) * 64 + w];
        }
        __syncthreads();
        #pragma unroll
        for (int k = 0; k < 32; ++k) {
            int idx = k * 256 + t;
            int w = idx >> 7, c = idx & 127;
            xTp[((size_t)((b * 66 + h + 1) * 66 + (w + 1))) * 512 + cb * 128 + c]
                = f2bf(lds[c][w]);
        }
        __syncthreads();
    }
}

// ---------------------------------------------------------------------------
// Kernel 2: Wd_eff[b][kpos][o][i] = sum_m F1[b,o,m] * Wd[m,i,kpos]   (bf16)
// ---------------------------------------------------------------------------
__global__ __launch_bounds__(256) void k_fold1(const float* __restrict__ f1,
                                               const float* __restrict__ wd,
                                               short* __restrict__ wd_eff) {
    int id = blockIdx.x * 256 + threadIdx.x;
    int i = id & 511;
    int o = (id >> 9) & 31;
    int b = id >> 14;
    float acc[9];
    #pragma unroll
    for (int k = 0; k < 9; ++k) acc[k] = 0.f;
    for (int m = 0; m < 32; ++m) {
        float f = f1[(b * 32 + o) * 32 + m];
        const float* wrow = wd + ((size_t)m * 512 + i) * 9;
        #pragma unroll
        for (int k = 0; k < 9; ++k) acc[k] += f * wrow[k];
    }
    #pragma unroll
    for (int k = 0; k < 9; ++k)
        wd_eff[(((size_t)b * 9 + k) * 32 + o) * 512 + i] = f2bf(acc[k]);
}

// ---------------------------------------------------------------------------
// Kernel 3: Wu_eff[b][kpos][O][c] = sum_m Wu[O,m,kpos] * F2[b,m,c]   (bf16)
// ---------------------------------------------------------------------------
__global__ __launch_bounds__(256) void k_fold2(const float* __restrict__ f2,
                                               const float* __restrict__ wu,
                                               short* __restrict__ wu_eff) {
    int id = blockIdx.x * 256 + threadIdx.x;   // ((b*9+kpos)*512 + O)*32 + c
    int c = id & 31;
    int O = (id >> 5) & 511;
    int rest = id >> 14;   // b*9 + kpos
    int kpos = rest % 9;
    int b = rest / 9;
    float acc = 0.f;
    #pragma unroll
    for (int m = 0; m < 32; ++m)
        acc += wu[((size_t)O * 32 + m) * 9 + kpos] * f2[(b * 32 + m) * 32 + c];
    wu_eff[id] = f2bf(acc);
}

// ---------------------------------------------------------------------------
// Kernel 4: bd_eff[b][o] = sum_m F1[b,o,m] * bd[m]   (f32), 1 block x 256
// ---------------------------------------------------------------------------
__global__ void k_bd(const float* __restrict__ f1, const float* __restrict__ bd,
                     float* __restrict__ bd_eff) {
    int t = threadIdx.x;
    int b = t >> 5, o = t & 31;
    float acc = 0.f;
    #pragma unroll
    for (int m = 0; m < 32; ++m) acc += f1[(b * 32 + o) * 32 + m] * bd[m];
    bd_eff[t] = acc;
}

// ---------------------------------------------------------------------------
// Kernel 5a: conv_down phase 1 — branch-free straight-line direct GEMM.
// wave = (b, s: 128-ch chunk, 32-px group). grid 1024 x 256.
// Fully unrolled 3x3x4; all addresses affine off two base pointers.
// partial[b][s][px][32ch] f32.
// ---------------------------------------------------------------------------
__global__ __launch_bounds__(256, 4) void k_conv_down_p(const short* __restrict__ xTp,
                                                        const short* __restrict__ wd_eff,
                                                        float* __restrict__ part) {
    int blk = blockIdx.x;          // 1024 = b(8) x pxg(128)
    int b = blk >> 7;
    int pxg = blk & 127;
    int h = pxg >> 1, w0 = (pxg & 1) * 32;
    int t = threadIdx.x;
    int lane = t & 63, s = t >> 6;             // s: channel chunk 0..3
    int lo = lane & 15, hi = lane >> 4;        // MFMA 16x16x32 lane split
    const int cb0 = s * 128;

    const short* bbase = xTp + ((size_t)((b * 66 + h) * 66 + (w0 + lo))) * 512
                             + cb0 + hi * 8;
    const short* abase = wd_eff + ((size_t)(b * 9) * 32 + lo) * 512 + cb0 + hi * 8;

    f32x4 acc[2][2] = {};                      // [Mtile][Ntile]

    #pragma unroll
    for (int kh = 0; kh < 3; ++kh) {
        #pragma unroll
        for (int kw = 0; kw < 3; ++kw) {
            const int kpos = kh * 3 + kw;
            #pragma unroll
            for (int kt = 0; kt < 4; ++kt) {
                short8 a0 = *(const short8*)(abase + kpos * 16384 + kt * 32);
                short8 a1 = *(const short8*)(abase + kpos * 16384 + 8192 + kt * 32);
                short8 b0 = *(const short8*)(bbase + (kh * 66 + kw) * 512 + kt * 32);
                short8 b1 = *(const short8*)(bbase + (kh * 66 + kw + 16) * 512 + kt * 32);
                acc[0][0] = __builtin_amdgcn_mfma_f32_16x16x32_bf16(a0, b0, acc[0][0], 0, 0, 0);
                acc[0][1] = __builtin_amdgcn_mfma_f32_16x16x32_bf16(a0, b1, acc[0][1], 0, 0, 0);
                acc[1][0] = __builtin_amdgcn_mfma_f32_16x16x32_bf16(a1, b0, acc[1][0], 0, 0, 0);
                acc[1][1] = __builtin_amdgcn_mfma_f32_16x16x32_bf16(a1, b1, acc[1][1], 0, 0, 0);
            }
        }
    }

    // D: col = px-in-tile = lo, row = ch = mt*16 + hi*4 + j
    #pragma unroll
    for (int nt = 0; nt < 2; ++nt) {
        int px = h * 64 + w0 + nt * 16 + lo;
        float* pb = part + ((size_t)(b * 4 + s) * 4096 + px) * 32;
        *(f32x4*)(pb + hi * 4)      = acc[0][nt];
        *(f32x4*)(pb + 16 + hi * 4) = acc[1][nt];
    }
}

// ---------------------------------------------------------------------------
// Kernel 5b: reduce 4 partials + bias, LeakyReLU -> padded tp[b][66][66][32]
// ---------------------------------------------------------------------------
__global__ __launch_bounds__(256) void k_down_reduce(const float* __restrict__ part,
                                                     const float* __restrict__ bd_eff,
                                                     short* __restrict__ tp) {
    int id = blockIdx.x * 256 + threadIdx.x;   // (b, px)
    int b = id >> 12, px = id & 4095;
    int h = px >> 6, w = px & 63;
    const float* p0 = part + ((size_t)(b * 4) * 4096 + px) * 32;
    const size_t sstr = (size_t)4096 * 32;
    short* o = tp + ((size_t)((b * 66 + h + 1) * 66 + (w + 1))) * 32;
    #pragma unroll
    for (int cq = 0; cq < 8; ++cq) {
        f32x4 v = *(const f32x4*)(p0 + cq * 4);
        #pragma unroll
        for (int s = 1; s < 4; ++s) {
            f32x4 u = *(const f32x4*)(p0 + s * sstr + cq * 4);
            v.x += u.x; v.y += u.y; v.z += u.z; v.w += u.w;
        }
        f32x4 bd4 = *(const f32x4*)(bd_eff + b * 32 + cq * 4);
        short4v sv;
        #pragma unroll
        for (int j = 0; j < 4; ++j) {
            float f = v[j] + bd4[j];
            f = f > 0.f ? f : 0.2f * f;
            sv[j] = f2bf(f);
        }
        *(short4v*)(o + cq * 4) = sv;
    }
}

// ---------------------------------------------------------------------------
// Kernel 6: conv_up + residual — LDS-free, barrier-free, branch-free.
// block = (b, h, 128-och quad); 4 waves: wave = 64 och x 32 px.
// MFMA 16x16x32, K=32 = all t channels in ONE kstep per kpos.
// All loads perfectly coalesced (1KB contiguous per instr).
// ---------------------------------------------------------------------------
__global__ __launch_bounds__(256, 4) void k_conv_up(const short* __restrict__ tp,
                                                    const short* __restrict__ wu_eff,
                                                    const float* __restrict__ content,
                                                    const float* __restrict__ bu,
                                                    float* __restrict__ out) {
    int blk = blockIdx.x;      // 2048 = b(8) x h(64) x ocq(4)
    int ocq = blk & 3;
    int h = (blk >> 2) & 63;
    int b = blk >> 8;
    int t = threadIdx.x;
    int lane = t & 63, wv = t >> 6;
    int lo = lane & 15, hi = lane >> 4;
    int Ob = ocq * 128 + (wv & 1) * 64;       // wave och base (64 ochs)
    int p0 = (wv >> 1) * 32;                  // wave px base (32 px)

    const short* bbase = tp + ((size_t)((b * 66 + h) * 66 + (p0 + lo))) * 32 + hi * 8;
    const short* abase = wu_eff + ((size_t)(b * 9 * 512) + Ob + lo) * 32 + hi * 8;

    f32x4 acc[4][2] = {};   // [mt: 16-och][nt: 16-px]

    #pragma unroll
    for (int kh = 0; kh < 3; ++kh) {
        #pragma unroll
        for (int kw = 0; kw < 3; ++kw) {
            const int kpos = kh * 3 + kw;
            short8 bf0 = *(const short8*)(bbase + (kh * 66 + kw) * 32);
            short8 bf1 = *(const short8*)(bbase + (kh * 66 + kw + 16) * 32);
            #pragma unroll
            for (int mt = 0; mt < 4; ++mt) {
                short8 af = *(const short8*)(abase + (kpos * 512 + mt * 16) * 32);
                acc[mt][0] = __builtin_amdgcn_mfma_f32_16x16x32_bf16(af, bf0, acc[mt][0], 0, 0, 0);
                acc[mt][1] = __builtin_amdgcn_mfma_f32_16x16x32_bf16(af, bf1, acc[mt][1], 0, 0, 0);
            }
        }
    }

    // epilogue: och = Ob + mt*16 + hi*4 + j, px = p0 + nt*16 + lo
    #pragma unroll
    for (int mt = 0; mt < 4; ++mt) {
        f32x4 bu4 = *(const f32x4*)(bu + Ob + mt * 16 + hi * 4);
        #pragma unroll
        for (int nt = 0; nt < 2; ++nt) {
            int px = p0 + nt * 16 + lo;
            #pragma unroll
            for (int j = 0; j < 4; ++j) {
                int O = Ob + mt * 16 + hi * 4 + j;
                size_t gidx = (((size_t)(b * 512 + O) * 64) + h) * 64 + px;
                out[gidx] = acc[mt][nt][j] + content[gidx] + bu4[j];
            }
        }
    }
}

// ---------------------------------------------------------------------------
extern "C" void kernel_launch(void* const* d_in, const int* in_sizes, int n_in,
                              void* d_out, int out_size, void* d_ws, size_t ws_size,
                              hipStream_t stream) {
    const float* content = (const float*)d_in[0];
    const float* f1      = (const float*)d_in[1];
    const float* f2      = (const float*)d_in[2];
    const float* wd      = (const float*)d_in[3];
    const float* bd      = (const float*)d_in[4];
    const float* wu      = (const float*)d_in[5];
    const float* bu      = (const float*)d_in[6];
    float* out = (float*)d_out;

    char* ws = (char*)d_ws;
    // layout (bytes):
    //   xTp   [8][66][66][512] bf16 : 35,684,352
    //   wd_eff                      :  2,359,296
    //   wu_eff                      :  2,359,296
    //   bd_eff                      :      1,024
    //   tp    [8][66][66][32] bf16  :  2,230,272
    //   part  [8][4][4096][32] f32  : 16,777,216   (total ~56.7 MiB)
    short* xTp    = (short*)(ws);
    short* wd_eff = (short*)(ws + 35684352);
    short* wu_eff = (short*)(ws + 38043648);
    float* bd_eff = (float*)(ws + 40402944);
    short* tp     = (short*)(ws + 40403968);
    float* part   = (float*)(ws + 42634240);

    k_zero_halo  <<<dim3(520),  dim3(256), 0, stream>>>(xTp, 64);
    k_zero_halo  <<<dim3(33),   dim3(256), 0, stream>>>(tp, 4);
    k_transpose  <<<dim3(512),  dim3(256), 0, stream>>>(content, xTp);
    k_fold1      <<<dim3(512),  dim3(256), 0, stream>>>(f1, wd, wd_eff);
    k_fold2      <<<dim3(4608), dim3(256), 0, stream>>>(f2, wu, wu_eff);
    k_bd         <<<dim3(1),    dim3(256), 0, stream>>>(f1, bd, bd_eff);
    k_conv_down_p<<<dim3(1024), dim3(256), 0, stream>>>(xTp, wd_eff, part);
    k_down_reduce<<<dim3(128),  dim3(256), 0, stream>>>(part, bd_eff, tp);
    k_conv_up    <<<dim3(2048), dim3(256), 0, stream>>>(tp, wu_eff, content, bu, out);
}

// Round 5
// 116.150 us; speedup vs baseline: 1.4435x; 1.4435x over previous
//
#include <hip/hip_runtime.h>
#include <hip/hip_bf16.h>

typedef __attribute__((ext_vector_type(8)))  short short8;
typedef __attribute__((ext_vector_type(4)))  float f32x4;

static __device__ inline short f2bf(float f) {
    union { __hip_bfloat16 h; unsigned short u; } cv;
    cv.h = __float2bfloat16(f);
    return (short)cv.u;
}

typedef __attribute__((address_space(3))) void lds_void;
typedef const __attribute__((address_space(1))) void glob_void;
static __device__ inline void gl16(const void* g, void* l) {
    // global -> LDS direct copy, 16 B/lane (1 KiB/wave). LDS dest is
    // wave-uniform base + lane*16 (HW-added); global src is per-lane.
    __builtin_amdgcn_global_load_lds((glob_void*)g, (lds_void*)l, 16, 0, 0);
}

// ---------------------------------------------------------------------------
// Kernel 0: zero halo of padded [nimg][66][rs][ch8*8] bf16 buffer (cols 0..65).
// ---------------------------------------------------------------------------
__global__ __launch_bounds__(256) void k_zero_halo(short* __restrict__ p, int nimg,
                                                   int rs, int ch8) {
    int id = blockIdx.x * 256 + threadIdx.x;
    int njobs = nimg * 260 * ch8;
    if (id >= njobs) return;
    int c8 = id % ch8;
    int rest = id / ch8;
    int px = rest % 260;
    int img = rest / 260;
    int row, col;
    if (px < 66)       { row = 0;  col = px; }
    else if (px < 132) { row = 65; col = px - 66; }
    else { int q = px - 132; row = 1 + (q >> 1); col = (q & 1) ? 65 : 0; }
    short8 z = {0, 0, 0, 0, 0, 0, 0, 0};
    *(short8*)(p + ((size_t)(img * 66 + row) * rs + col) * (ch8 * 8) + c8 * 8) = z;
}

// ---------------------------------------------------------------------------
// Kernel 1: content [B,512,64,64] f32 -> xTc [b][cs8][66][66][64] bf16,
// interior only, pre-swizzled within each 128B pixel-block: slot ^= (col&7).
// ---------------------------------------------------------------------------
__global__ __launch_bounds__(256) void k_transpose(const float* __restrict__ x,
                                                   short* __restrict__ xTc) {
    __shared__ float lds[128][65];
    int blk = blockIdx.x;
    int b = blk >> 6, h = blk & 63;
    int t = threadIdx.x;
    for (int cb = 0; cb < 4; ++cb) {
        #pragma unroll
        for (int k = 0; k < 32; ++k) {
            int idx = k * 256 + t;
            int c = idx >> 6, w = idx & 63;
            lds[c][w] = x[(((size_t)b * 512 + cb * 128 + c) * 64 + h) * 64 + w];
        }
        __syncthreads();
        #pragma unroll
        for (int k = 0; k < 4; ++k) {
            int j = k * 256 + t;       // 1024 jobs: (w, 16B-slot of 128 ch)
            int w = j >> 4, sl = j & 15;
            int cs = cb * 2 + (sl >> 3);
            int slotp = (sl & 7) ^ ((w + 1) & 7);
            short8 v;
            #pragma unroll
            for (int e = 0; e < 8; ++e) v[e] = f2bf(lds[sl * 8 + e][w]);
            *(short8*)(xTc + (((size_t)(b * 8 + cs) * 66 + (h + 1)) * 66 + (w + 1)) * 64
                           + slotp * 8) = v;
        }
        __syncthreads();
    }
}

// ---------------------------------------------------------------------------
// Kernel 2: Wd_eff fragment-major: wd_frag[b][s2][ci4][kpos9][kt2][mt2][512]
// frag elem = lo*32 + hi*8 + e  (och lo 0..15, ch = kt*32+hi*8+e within chunk)
// ---------------------------------------------------------------------------
__global__ __launch_bounds__(256) void k_fold1(const float* __restrict__ f1,
                                               const float* __restrict__ wd,
                                               short* __restrict__ wd_frag) {
    int id = blockIdx.x * 256 + threadIdx.x;
    int i = id & 511;
    int o = (id >> 9) & 31;
    int b = id >> 14;
    float acc[9];
    #pragma unroll
    for (int k = 0; k < 9; ++k) acc[k] = 0.f;
    for (int m = 0; m < 32; ++m) {
        float f = f1[(b * 32 + o) * 32 + m];
        const float* wrow = wd + ((size_t)m * 512 + i) * 9;
        #pragma unroll
        for (int k = 0; k < 9; ++k) acc[k] += f * wrow[k];
    }
    int s = i >> 8, ci = (i >> 6) & 3, kt = (i >> 5) & 1, hi = (i >> 3) & 3, e = i & 7;
    int mt = o >> 4, lo = o & 15;
    #pragma unroll
    for (int k = 0; k < 9; ++k)
        wd_frag[((((((size_t)(b * 2 + s) * 4 + ci) * 9 + k) * 2 + kt) * 2 + mt) * 512)
                + lo * 32 + hi * 8 + e] = f2bf(acc[k]);
}

// ---------------------------------------------------------------------------
// Kernel 3: Wu_eff fragment-major: wu_frag[b][kpos9][g32][512]
// frag elem = lo*32 + hi*8 + e (och = g*16+lo, t-ch = hi*8+e)
// ---------------------------------------------------------------------------
__global__ __launch_bounds__(256) void k_fold2(const float* __restrict__ f2,
                                               const float* __restrict__ wu,
                                               short* __restrict__ wu_frag) {
    int id = blockIdx.x * 256 + threadIdx.x;
    int e = id & 7, hi = (id >> 3) & 3, lo = (id >> 5) & 15, g = (id >> 9) & 31;
    int rest = id >> 14;
    int kpos = rest % 9;
    int b = rest / 9;
    int O = g * 16 + lo, c = hi * 8 + e;
    float acc = 0.f;
    #pragma unroll
    for (int m = 0; m < 32; ++m)
        acc += wu[((size_t)O * 32 + m) * 9 + kpos] * f2[(b * 32 + m) * 32 + c];
    wu_frag[(((size_t)(b * 9 + kpos) * 32 + g) * 512) + lo * 32 + hi * 8 + e] = f2bf(acc);
}

// ---------------------------------------------------------------------------
// Kernel 4: bd_eff[b][o] = sum_m F1[b,o,m] * bd[m]
// ---------------------------------------------------------------------------
__global__ void k_bd(const float* __restrict__ f1, const float* __restrict__ bd,
                     float* __restrict__ bd_eff) {
    int t = threadIdx.x;
    int b = t >> 5, o = t & 31;
    float acc = 0.f;
    #pragma unroll
    for (int m = 0; m < 32; ++m) acc += f1[(b * 32 + o) * 32 + m] * bd[m];
    bd_eff[t] = acc;
}

// ---------------------------------------------------------------------------
// Kernel 5a: conv_down — m97-style pipeline.
// block = (b, rp: out rows 2rp..2rp+1, s: K-half). grid 512.
// 4 chunks of 64ch; chunk tile = 4 rows x 66 cols x 64 ch = 33 KiB staged
// via 33 x global_load_lds(1KiB), double-buffered, 1 barrier per chunk.
// wave = 32 och x (row lr, col-half ch): acc 2mt x 2nt.
// ---------------------------------------------------------------------------
__global__ __launch_bounds__(256, 2) void k_conv_down(const short* __restrict__ xTc,
                                                      const short* __restrict__ wd_frag,
                                                      float* __restrict__ part) {
    __shared__ __align__(16) short xs[2][16896];
    int blk = blockIdx.x;          // 512 = b(8) x rp(32) x s(2)
    int s = blk & 1, rp = (blk >> 1) & 31, b = blk >> 6;
    int t = threadIdx.x, lane = t & 63, wv = t >> 6;
    int lr = wv >> 1, chh = wv & 1;
    int cb0 = chh * 32;
    int lo = lane & 15, hi = lane >> 4;
    int R0 = 2 * rp;

    const size_t CSTR = (size_t)66 * 66 * 128;          // bytes per cs-plane
    const char* sbase = (const char*)xTc
                      + ((size_t)(b * 8 + s * 4) * 66 + R0) * (66 * 128);

    // prologue: stage chunk 0
    for (int i = wv; i < 33; i += 4)
        gl16(sbase + i * 1024 + lane * 16, (char*)&xs[0][0] + i * 1024);
    __syncthreads();

    f32x4 acc[2][2] = {};
    const short* ab0 = wd_frag + (size_t)(b * 2 + s) * 4 * 9 * 2 * 2 * 512;

    #pragma unroll
    for (int ci = 0; ci < 4; ++ci) {
        if (ci < 3)
            for (int i = wv; i < 33; i += 4)
                gl16(sbase + (ci + 1) * CSTR + i * 1024 + lane * 16,
                     (char*)&xs[(ci + 1) & 1][0] + i * 1024);
        const short* ab = ab0 + (size_t)ci * 9 * 2 * 2 * 512;
        const short* xb = &xs[ci & 1][0];
        #pragma unroll
        for (int kh = 0; kh < 3; ++kh) {
            #pragma unroll
            for (int kw = 0; kw < 3; ++kw) {
                const int kpos = kh * 3 + kw;
                #pragma unroll
                for (int kt = 0; kt < 2; ++kt) {
                    short8 a0 = *(const short8*)(ab + ((kpos * 2 + kt) * 2 + 0) * 512
                                                    + lo * 32 + hi * 8);
                    short8 a1 = *(const short8*)(ab + ((kpos * 2 + kt) * 2 + 1) * 512
                                                    + lo * 32 + hi * 8);
                    short8 b0, b1;
                    #pragma unroll
                    for (int nt = 0; nt < 2; ++nt) {
                        int g = cb0 + nt * 16 + lo + kw;      // padded col 0..65
                        int sw = ((kt * 4 + hi) ^ (g & 7)) << 3;
                        short8 bf = *(const short8*)(xb + ((lr + kh) * 66 + g) * 64 + sw);
                        if (nt == 0) b0 = bf; else b1 = bf;
                    }
                    acc[0][0] = __builtin_amdgcn_mfma_f32_16x16x32_bf16(a0, b0, acc[0][0], 0, 0, 0);
                    acc[0][1] = __builtin_amdgcn_mfma_f32_16x16x32_bf16(a0, b1, acc[0][1], 0, 0, 0);
                    acc[1][0] = __builtin_amdgcn_mfma_f32_16x16x32_bf16(a1, b0, acc[1][0], 0, 0, 0);
                    acc[1][1] = __builtin_amdgcn_mfma_f32_16x16x32_bf16(a1, b1, acc[1][1], 0, 0, 0);
                }
            }
        }
        __syncthreads();
    }

    #pragma unroll
    for (int nt = 0; nt < 2; ++nt) {
        int px = (R0 + lr) * 64 + cb0 + nt * 16 + lo;
        float* pb = part + ((size_t)(b * 2 + s) * 4096 + px) * 32;
        *(f32x4*)(pb + hi * 4)      = acc[0][nt];
        *(f32x4*)(pb + 16 + hi * 4) = acc[1][nt];
    }
}

// ---------------------------------------------------------------------------
// Kernel 5b: reduce 2 partials + bias + LeakyReLU -> tp2[b][66][80][32]
// (swizzled: 16B slot ^= (padded col)&3)
// ---------------------------------------------------------------------------
__global__ __launch_bounds__(256) void k_down_reduce(const float* __restrict__ part,
                                                     const float* __restrict__ bd_eff,
                                                     short* __restrict__ tp2) {
    int id = blockIdx.x * 256 + threadIdx.x;   // (b, px)
    int b = id >> 12, px = id & 4095;
    int h = px >> 6, w = px & 63;
    const float* p0 = part + ((size_t)(b * 2) * 4096 + px) * 32;
    const float* p1 = p0 + (size_t)4096 * 32;
    short* o = tp2 + ((size_t)(b * 66 + h + 1) * 80 + (w + 1)) * 32;
    int wm = (w + 1) & 3;
    #pragma unroll
    for (int sl = 0; sl < 4; ++sl) {
        short8 sv;
        #pragma unroll
        for (int e = 0; e < 8; ++e) {
            int c = sl * 8 + e;
            float f = p0[c] + p1[c] + bd_eff[b * 32 + c];
            f = f > 0.f ? f : 0.2f * f;
            sv[e] = f2bf(f);
        }
        *(short8*)(o + ((sl ^ wm) * 8)) = sv;
    }
}

// ---------------------------------------------------------------------------
// Kernel 6: conv_up + residual.  block = (b, 2 rows, 128 och). grid 1024.
// t-tile 4 rows x 80 x 32 = 20 KiB staged once (20 x gload_lds), 1 barrier,
// then straight-line 9-kpos compute. wave = 64 och x 64 px: 4mt x 4nt.
// ---------------------------------------------------------------------------
__global__ __launch_bounds__(256, 2) void k_conv_up(const short* __restrict__ tp2,
                                                    const short* __restrict__ wu_frag,
                                                    const float* __restrict__ content,
                                                    const float* __restrict__ bu,
                                                    float* __restrict__ out) {
    __shared__ __align__(16) short tl[10240];   // 4 x 80 x 32
    int blk = blockIdx.x;      // 1024 = b(8) x hb(32) x ocq(4)
    int ocq = blk & 3, hb = (blk >> 2) & 31, b = blk >> 7;
    int t = threadIdx.x, lane = t & 63, wv = t >> 6;
    int lr = wv >> 1, oh = wv & 1;
    int lo = lane & 15, hi = lane >> 4;
    int Ob = ocq * 128 + oh * 64;
    int R0 = 2 * hb;

    const char* sbase = (const char*)tp2 + ((size_t)(b * 66 + R0) * 80) * 64;
    for (int i = wv; i < 20; i += 4)
        gl16(sbase + i * 1024 + lane * 16, (char*)tl + i * 1024);
    __syncthreads();

    f32x4 acc[4][4] = {};
    const short* ab0 = wu_frag + ((size_t)(b * 9) * 32 + (Ob >> 4)) * 512;

    #pragma unroll
    for (int kh = 0; kh < 3; ++kh) {
        #pragma unroll
        for (int kw = 0; kw < 3; ++kw) {
            const int kpos = kh * 3 + kw;
            short8 bf0, bf1, bf2, bf3;
            #pragma unroll
            for (int nt = 0; nt < 4; ++nt) {
                int g = nt * 16 + lo + kw;                 // padded col 0..65
                short8 bf = *(const short8*)(tl + ((lr + kh) * 80 + g) * 32
                                                + ((hi ^ (g & 3)) << 3));
                if (nt == 0) bf0 = bf; else if (nt == 1) bf1 = bf;
                else if (nt == 2) bf2 = bf; else bf3 = bf;
            }
            #pragma unroll
            for (int mt = 0; mt < 4; ++mt) {
                short8 af = *(const short8*)(ab0 + ((size_t)kpos * 32 + mt) * 512
                                                 + lo * 32 + hi * 8);
                acc[mt][0] = __builtin_amdgcn_mfma_f32_16x16x32_bf16(af, bf0, acc[mt][0], 0, 0, 0);
                acc[mt][1] = __builtin_amdgcn_mfma_f32_16x16x32_bf16(af, bf1, acc[mt][1], 0, 0, 0);
                acc[mt][2] = __builtin_amdgcn_mfma_f32_16x16x32_bf16(af, bf2, acc[mt][2], 0, 0, 0);
                acc[mt][3] = __builtin_amdgcn_mfma_f32_16x16x32_bf16(af, bf3, acc[mt][3], 0, 0, 0);
            }
        }
    }

    int h = R0 + lr;
    #pragma unroll
    for (int mt = 0; mt < 4; ++mt) {
        f32x4 bu4 = *(const f32x4*)(bu + Ob + mt * 16 + hi * 4);
        #pragma unroll
        for (int nt = 0; nt < 4; ++nt) {
            int px = nt * 16 + lo;
            #pragma unroll
            for (int j = 0; j < 4; ++j) {
                int O = Ob + mt * 16 + hi * 4 + j;
                size_t gidx = (((size_t)(b * 512 + O) * 64) + h) * 64 + px;
                out[gidx] = acc[mt][nt][j] + content[gidx] + bu4[j];
            }
        }
    }
}

// ---------------------------------------------------------------------------
extern "C" void kernel_launch(void* const* d_in, const int* in_sizes, int n_in,
                              void* d_out, int out_size, void* d_ws, size_t ws_size,
                              hipStream_t stream) {
    const float* content = (const float*)d_in[0];
    const float* f1      = (const float*)d_in[1];
    const float* f2      = (const float*)d_in[2];
    const float* wd      = (const float*)d_in[3];
    const float* bd      = (const float*)d_in[4];
    const float* wu      = (const float*)d_in[5];
    const float* bu      = (const float*)d_in[6];
    float* out = (float*)d_out;

    char* ws = (char*)d_ws;
    // layout (bytes):
    //   xTc    [8][8][66][66][64] bf16 : 35,684,352
    //   wd_frag                        :  2,359,296
    //   wu_frag                        :  2,359,296
    //   bd_eff                         :      1,024
    //   tp2    [8][66][80][32] bf16    :  2,703,360
    //   part   [8][2][4096][32] f32    :  8,388,608   (total ~49.1 MiB)
    short* xTc     = (short*)(ws);
    short* wd_frag = (short*)(ws + 35684352);
    short* wu_frag = (short*)(ws + 38043648);
    float* bd_eff  = (float*)(ws + 40402944);
    short* tp2     = (short*)(ws + 40403968);
    float* part    = (float*)(ws + 43107328);

    k_zero_halo  <<<dim3(520),  dim3(256), 0, stream>>>(xTc, 64, 66, 8);
    k_zero_halo  <<<dim3(33),   dim3(256), 0, stream>>>(tp2, 8, 80, 4);
    k_transpose  <<<dim3(512),  dim3(256), 0, stream>>>(content, xTc);
    k_fold1      <<<dim3(512),  dim3(256), 0, stream>>>(f1, wd, wd_frag);
    k_fold2      <<<dim3(4608), dim3(256), 0, stream>>>(f2, wu, wu_frag);
    k_bd         <<<dim3(1),    dim3(256), 0, stream>>>(f1, bd, bd_eff);
    k_conv_down  <<<dim3(512),  dim3(256), 0, stream>>>(xTc, wd_frag, part);
    k_down_reduce<<<dim3(128),  dim3(256), 0, stream>>>(part, bd_eff, tp2);
    k_conv_up    <<<dim3(1024), dim3(256), 0, stream>>>(tp2, wu_frag, content, bu, out);
}